// Round 5
// baseline (167.677 us; speedup 1.0000x reference)
//
#include <hip/hip_runtime.h>

#define NB 16
#define NH 4
#define HD 128
#define HW 1024
#define CIN 512

typedef short s16x8 __attribute__((ext_vector_type(8)));
typedef short s16x4 __attribute__((ext_vector_type(4)));
typedef float f32x4 __attribute__((ext_vector_type(4)));

static __device__ __forceinline__ short f2bf(float f) {
    union { float f; unsigned u; } v; v.f = f;
    unsigned r = v.u + 0x7fffu + ((v.u >> 16) & 1u);   // round-to-nearest-even
    return (short)(r >> 16);
}

// async global->LDS DMA, 16B per lane. LDS dest is wave-uniform base + lane*16
// (linear); global src is per-lane (carries the XOR swizzle).
static __device__ __forceinline__ void gload16(const short* g, short* l) {
    __builtin_amdgcn_global_load_lds(
        (const __attribute__((address_space(1))) unsigned int*)g,
        (__attribute__((address_space(3))) unsigned int*)l, 16, 0, 0);
}

// ---------------------------------------------------------------------------
// prep: x[b][c][p] fp32 -> xT[b][p][c] bf16 (32x32 LDS tile transpose)
//       W[o][c]   fp32 -> Wb bf16 (elementwise)
// ---------------------------------------------------------------------------
__global__ __launch_bounds__(256) void prep_xw(
    const float* __restrict__ x, const float* __restrict__ w,
    short* __restrict__ xT, short* __restrict__ Wb)
{
    int blk = blockIdx.x;
    if (blk < NB * 16 * 32) {                  // 8192 transpose tiles
        int b = blk >> 9, rem = blk & 511;
        int ct = rem >> 5, pt = rem & 31;      // 16 c-tiles x 32 p-tiles
        __shared__ float tile[32][33];
        int tc = threadIdx.x >> 5;             // 0..7
        int tp = threadIdx.x & 31;             // 0..31
        const float* xb = x + ((size_t)b * CIN + ct * 32) * HW + pt * 32;
        #pragma unroll
        for (int i = 0; i < 4; i++)
            tile[tc + i * 8][tp] = xb[(size_t)(tc + i * 8) * HW + tp];
        __syncthreads();
        int p = threadIdx.x >> 3, cq = threadIdx.x & 7;
        short* xo = xT + ((size_t)b * HW + pt * 32 + p) * CIN + ct * 32 + cq * 4;
        s16x4 o4 = { f2bf(tile[cq * 4 + 0][p]), f2bf(tile[cq * 4 + 1][p]),
                     f2bf(tile[cq * 4 + 2][p]), f2bf(tile[cq * 4 + 3][p]) };
        *reinterpret_cast<s16x4*>(xo) = o4;
    } else {
        int wb = blk - NB * 16 * 32;           // 0..767, 1024 elems each
        size_t base = (size_t)wb * 1024 + threadIdx.x * 4;
        const float4 v = *reinterpret_cast<const float4*>(w + base);
        s16x4 o4 = { f2bf(v.x), f2bf(v.y), f2bf(v.z), f2bf(v.w) };
        *reinterpret_cast<s16x4*>(Wb + base) = o4;
    }
}

// ---------------------------------------------------------------------------
// qkv projection GEMM, BK=64, m97 structure: global_load_lds DMA staging
// (width 16), single-buffered LDS, 2 barriers per K-step. Content keeps the
// 16B-chunk XOR swizzle (phys = c ^ (row&7)) via PRE-SWIZZLED per-lane global
// source + linear LDS dest (m173 pattern) -> frag reads & epilogues unchanged.
//   s=0: Q = val * (128^-0.5 * log2e)   [p][d]
//   s=1: K' = val + pos_h + pos_w       [p][d]
//   s=2: Vt = val                       [d][p]  -- p PERMUTED within 32-groups
//        (slot = 8*qs + 4*t + r  <-  u = 16*t + 4*qs + r), so attn's PV can
//        consume P directly from the S^T C-layout registers (no LDS trip).
// ---------------------------------------------------------------------------
__global__ __launch_bounds__(256, 3) void qkv_proj(
    const short* __restrict__ xT, const short* __restrict__ Wb,
    const float* __restrict__ pos_h, const float* __restrict__ pos_w,
    short* __restrict__ Q, short* __restrict__ Kp, short* __restrict__ Vt)
{
    __shared__ __align__(1024) char smem[34816];
    short* As = (short*)smem;               // [128][64] content-swizzled
    short* Bs = As + 128 * 64;              // [128][64] content-swizzled
    short* vb = (short*)smem;               // [128][136] reused for V epilogue

    const int pt = blockIdx.x, ot = blockIdx.y, b = blockIdx.z;
    const int tid = threadIdx.x;
    const int wave = tid >> 6, lane = tid & 63;
    const int l16 = lane & 15, quad = lane >> 4;
    const int wm = (wave & 1) * 64, wn = (wave >> 1) * 64;
    const int o0 = ot * 128, p0 = pt * 128;

    const short* xb = xT + (size_t)b * HW * CIN;

    // DMA staging geometry: wave w covers rows [w*32, w*32+32); instr j covers
    // 8 rows (1024 B). Lane: row_local = j*8 + (lane>>3), phys chunk = lane&7.
    // Source chunk = phys ^ (row&7); row&7 == lane>>3 (j*8, w*32 are 0 mod 8).
    const int r8 = lane >> 3, c8 = lane & 7;
    const int sch = c8 ^ r8;                  // pre-swizzled source chunk
    const short* wsrc = Wb + (size_t)(o0 + wave * 32 + r8) * CIN + sch * 8;
    const short* xsrc = xb + (size_t)(p0 + wave * 32 + r8) * CIN + sch * 8;
    short* adst = As + wave * 2048;           // + j*512 shorts (= j*1024 B)
    short* bdst = Bs + wave * 2048;

    f32x4 acc[4][4];
    #pragma unroll
    for (int i = 0; i < 4; i++)
        #pragma unroll
        for (int j = 0; j < 4; j++)
            acc[i][j] = f32x4{0.f, 0.f, 0.f, 0.f};

    #pragma unroll 1
    for (int kc = 0; kc < CIN; kc += 64) {
        #pragma unroll
        for (int j = 0; j < 4; j++) {
            gload16(wsrc + kc + (size_t)(j * 8) * CIN, adst + j * 512);
            gload16(xsrc + kc + (size_t)(j * 8) * CIN, bdst + j * 512);
        }
        __syncthreads();   // compiler drains vmcnt(0) before barrier
        #pragma unroll
        for (int kk = 0; kk < 2; kk++) {
            s16x8 aF[4], bF[4];
            #pragma unroll
            for (int mi = 0; mi < 4; mi++)
                aF[mi] = *(const s16x8*)(As + (wm + mi * 16 + l16) * 64
                                         + (((kk * 4 + quad) ^ (l16 & 7)) * 8));
            #pragma unroll
            for (int ni = 0; ni < 4; ni++)
                bF[ni] = *(const s16x8*)(Bs + (wn + ni * 16 + l16) * 64
                                         + (((kk * 4 + quad) ^ (l16 & 7)) * 8));
            #pragma unroll
            for (int mi = 0; mi < 4; mi++)
                #pragma unroll
                for (int ni = 0; ni < 4; ni++)
                    acc[mi][ni] = __builtin_amdgcn_mfma_f32_16x16x32_bf16(
                        aF[mi], bF[ni], acc[mi][ni], 0, 0, 0);
        }
        __syncthreads();   // all reads done before next DMA overwrites
    }

    const int s = ot >> 2, h = ot & 3;
    const size_t bh = (size_t)(b * NH + h);

    if (s == 0) {
        const float qs = 0.08838834764831845f * 1.4426950408889634f; // scale*log2e
        short* Qb = Q + bh * (size_t)(HW * HD);
        #pragma unroll
        for (int mi = 0; mi < 4; mi++) {
            int d0 = wm + mi * 16 + quad * 4;
            #pragma unroll
            for (int ni = 0; ni < 4; ni++) {
                int p = p0 + wn + ni * 16 + l16;
                f32x4 a = acc[mi][ni];
                s16x4 o4 = { f2bf(a.x * qs), f2bf(a.y * qs),
                             f2bf(a.z * qs), f2bf(a.w * qs) };
                *reinterpret_cast<s16x4*>(Qb + (size_t)p * HD + d0) = o4;
            }
        }
    } else if (s == 1) {
        short* Kb = Kp + bh * (size_t)(HW * HD);
        #pragma unroll
        for (int mi = 0; mi < 4; mi++) {
            int d0 = wm + mi * 16 + quad * 4;
            #pragma unroll
            for (int ni = 0; ni < 4; ni++) {
                int p = p0 + wn + ni * 16 + l16;
                const float4 eh = *reinterpret_cast<const float4*>(pos_h + (p >> 5) * HD + d0);
                const float4 ew = *reinterpret_cast<const float4*>(pos_w + (p & 31) * HD + d0);
                f32x4 a = acc[mi][ni];
                s16x4 o4 = { f2bf(a.x + eh.x + ew.x), f2bf(a.y + eh.y + ew.y),
                             f2bf(a.z + eh.z + ew.z), f2bf(a.w + eh.w + ew.w) };
                *reinterpret_cast<s16x4*>(Kb + (size_t)p * HD + d0) = o4;
            }
        }
    } else {
        __syncthreads();   // done with As/Bs before vb overlay
        #pragma unroll
        for (int mi = 0; mi < 4; mi++) {
            int d0 = wm + mi * 16 + quad * 4;
            #pragma unroll
            for (int ni = 0; ni < 4; ni++) {
                int p = wn + ni * 16 + l16;
                f32x4 a = acc[mi][ni];
                vb[(d0 + 0) * 136 + p] = f2bf(a.x);
                vb[(d0 + 1) * 136 + p] = f2bf(a.y);
                vb[(d0 + 2) * 136 + p] = f2bf(a.z);
                vb[(d0 + 3) * 136 + p] = f2bf(a.w);
            }
        }
        __syncthreads();
        short* Vb = Vt + bh * (size_t)(HD * HW);
        int d = tid >> 1, half = tid & 1;
        // key-permuted store: out slot group g=(half*2+(j>>2)), qs=(j&3):
        //   slots 8qs..8qs+3 (t=0) <- u = g*32 + 4qs + r
        //   slots 8qs+4..+7 (t=1) <- u = g*32 + 16 + 4qs + r
        #pragma unroll
        for (int j = 0; j < 8; j++) {
            const short* row = vb + d * 136;
            int base = (half * 2 + (j >> 2)) * 32 + (j & 3) * 4;
            s16x4 lo = *(const s16x4*)(row + base);
            s16x4 hi = *(const s16x4*)(row + base + 16);
            s16x8 v8 = { lo[0], lo[1], lo[2], lo[3],
                         hi[0], hi[1], hi[2], hi[3] };
            *reinterpret_cast<s16x8*>(Vb + (size_t)d * HW + p0 + half * 64 + j * 8) = v8;
        }
    }
}

// ---------------------------------------------------------------------------
// Fused attention: 256 threads = 4 waves x 32 Q-ROWS, kt = 64 keys x 16 iters.
// R5: staging converted to global_load_lds DMA (linear LDS dest + pre-XOR'd
// per-lane global source; content layout identical to reg-staged version).
// Removes per wave-iter: 8 ds_write_b128 (20% of LDS wave-issues), 8 global
// b128 VGPR round-trips + addr VALU, and 16 staging VGPRs. DMA for tile kt+1
// issued at top of iter kt into buf nxt; the compiler's vmcnt(0) drain before
// the end-of-iter barrier guarantees residency. ONE barrier per iter.
// P NEVER TOUCHES LDS (bank conflicts = 0, verified R3): V stored key-
// PERMUTED (see qkv_proj) so S^T's C-layout regs are directly PV's A-frags.
// Grid 512 (bh = flat&63: XCD-affine), 2 blocks/CU (66KB LDS, grid-limited).
// ---------------------------------------------------------------------------
__global__ __launch_bounds__(256, 2) void attn_fused(
    const short* __restrict__ Q, const short* __restrict__ Kp,
    const short* __restrict__ Vt, float* __restrict__ out)
{
    __shared__ __align__(1024) short Ks[2][64 * 128];   // [buf][key][d] swz: c^(key&15)
    __shared__ __align__(1024) short Vs[2][128 * 64];   // [buf][d][slot] swz: c^(d&7)

    const int flat = blockIdx.x;
    const int qt = flat >> 6;              // 0..7
    const int bh = flat & 63;              // XCD-affine: bh%8 == blockIdx%8
    const int tid = threadIdx.x;
    const int wave = tid >> 6, lane = tid & 63;
    const int l16 = lane & 15, quad = lane >> 4;

    const short* Qb = Q + (size_t)bh * (HW * HD);
    const short* Kb = Kp + (size_t)bh * (HW * HD);
    const short* Vb = Vt + (size_t)bh * (HD * HW);

    const int q0 = qt * 128 + wave * 32;

    // Q fragments (B-operand for S^T): this wave's 32 rows, K=128 -> 2x4 frags
    s16x8 bQ[2][4];
    #pragma unroll
    for (int nt = 0; nt < 2; nt++)
        #pragma unroll
        for (int kk = 0; kk < 4; kk++)
            bQ[nt][kk] = *(const s16x8*)(Qb + (size_t)(q0 + nt * 16 + l16) * HD
                                         + kk * 32 + quad * 8);

    s16x8 ones;
    #pragma unroll
    for (int j = 0; j < 8; j++) ones[j] = (short)0x3F80;   // bf16 1.0

    f32x4 Oacc[2][8];
    #pragma unroll
    for (int mt = 0; mt < 2; mt++)
        #pragma unroll
        for (int dt = 0; dt < 8; dt++)
            Oacc[mt][dt] = f32x4{0.f, 0.f, 0.f, 0.f};
    f32x4 lacc[2] = { f32x4{0.f, 0.f, 0.f, 0.f}, f32x4{0.f, 0.f, 0.f, 0.f} };

    // DMA staging geometry (32 KB/tile = 32 instrs of 1KB; 8 per wave):
    // K instr j: keys wave*16 + j*4 .. +4. lane: key = base + (lane>>4),
    //   phys chunk = lane&15, src chunk = (lane&15) ^ (key&15),
    //   key&15 = j*4 + (lane>>4)  (wave*16 == 0 mod 16).
    // V instr j: d = wave*32 + j*8 .. +8. lane: d = base + (lane>>3),
    //   phys chunk = lane&7, src chunk = (lane&7) ^ (lane>>3)  (d&7 == lane>>3).
    const int kRow = lane >> 4;            // 0..3
    const int vRow = lane >> 3;            // 0..7
    const int vSch = (lane & 7) ^ vRow;    // V source chunk (j-independent)

    #define STAGE(buf, tile)                                                  \
        do {                                                                  \
            _Pragma("unroll")                                                 \
            for (int j = 0; j < 4; j++) {                                     \
                int kkey = wave * 16 + j * 4 + kRow;                          \
                gload16(Kb + ((size_t)((tile) * 64 + kkey)) * HD              \
                           + (((lane & 15) ^ (j * 4 + kRow)) * 8),            \
                        &Ks[buf][(wave * 16 + j * 4) * 128] + lane * 8);      \
                int vd = wave * 32 + j * 8 + vRow;                            \
                gload16(Vb + (size_t)vd * HW + (tile) * 64 + vSch * 8,        \
                        &Vs[buf][(wave * 32 + j * 8) * 64] + lane * 8);       \
            }                                                                 \
        } while (0)

    STAGE(0, 0);           // tile 0 -> buf0 (vmcnt drained by barrier below)
    __syncthreads();

    #pragma unroll 1
    for (int kt = 0; kt < 16; kt++) {
        const int cur = kt & 1, nxt = cur ^ 1;
        const short* ks = Ks[cur];
        const short* vs = Vs[cur];

        // issue DMA for tile kt+1 into nxt (overlaps this iter's compute;
        // nxt's last readers finished at iter kt-1, ordered by its barrier)
        STAGE(nxt, (kt + 1) & 15);   // wrap at end: harmless L2-hot reload

        // ---- S^T: 64 keys x 32 qrows (aK shared across both q-tiles)
        f32x4 c[4][2];
        __builtin_amdgcn_s_setprio(1);
        #pragma unroll
        for (int mtp = 0; mtp < 4; mtp++) {
            s16x8 aK[4];
            #pragma unroll
            for (int kk = 0; kk < 4; kk++)
                aK[kk] = *(const s16x8*)(ks + (mtp * 16 + l16) * 128
                                         + (((kk * 4 + quad) ^ l16) * 8));
            c[mtp][0] = f32x4{0.f, 0.f, 0.f, 0.f};
            c[mtp][1] = f32x4{0.f, 0.f, 0.f, 0.f};
            #pragma unroll
            for (int kk = 0; kk < 4; kk++) {
                c[mtp][0] = __builtin_amdgcn_mfma_f32_16x16x32_bf16(
                    aK[kk], bQ[0][kk], c[mtp][0], 0, 0, 0);
                c[mtp][1] = __builtin_amdgcn_mfma_f32_16x16x32_bf16(
                    aK[kk], bQ[1][kk], c[mtp][1], 0, 0, 0);
            }
        }
        __builtin_amdgcn_s_setprio(0);

        // ---- P = exp2(S') packed ENTIRELY in registers (V rows permuted to
        //      match the C-layout keys each lane holds). Two 32-key halves.
        #pragma unroll
        for (int h = 0; h < 2; h++) {
            s16x8 aP[2];
            #pragma unroll
            for (int mt = 0; mt < 2; mt++) {
                f32x4 e0 = c[2 * h][mt], e1 = c[2 * h + 1][mt];
                aP[mt] = s16x8{
                    f2bf(__builtin_amdgcn_exp2f(e0[0])),
                    f2bf(__builtin_amdgcn_exp2f(e0[1])),
                    f2bf(__builtin_amdgcn_exp2f(e0[2])),
                    f2bf(__builtin_amdgcn_exp2f(e0[3])),
                    f2bf(__builtin_amdgcn_exp2f(e1[0])),
                    f2bf(__builtin_amdgcn_exp2f(e1[1])),
                    f2bf(__builtin_amdgcn_exp2f(e1[2])),
                    f2bf(__builtin_amdgcn_exp2f(e1[3])) };
            }

            __builtin_amdgcn_s_setprio(1);
            #pragma unroll
            for (int mt = 0; mt < 2; mt++)
                lacc[mt] = __builtin_amdgcn_mfma_f32_16x16x32_bf16(
                    aP[mt], ones, lacc[mt], 0, 0, 0);

            #pragma unroll
            for (int dt = 0; dt < 8; dt++) {
                s16x8 bV = *(const s16x8*)(vs + (dt * 16 + l16) * 64
                                           + (((h * 4 + quad) ^ (l16 & 7)) * 8));
                #pragma unroll
                for (int mt = 0; mt < 2; mt++)
                    Oacc[mt][dt] = __builtin_amdgcn_mfma_f32_16x16x32_bf16(
                        aP[mt], bV, Oacc[mt][dt], 0, 0, 0);
            }
            __builtin_amdgcn_s_setprio(0);
        }
        __syncthreads();   // drains DMA (nxt ready) + orders cur reads
    }
    #undef STAGE

    // epilogue: O/l, stored transposed -> out[b][h][d][p] FP32
    float* ob = out + (size_t)bh * (HD * HW);
    #pragma unroll
    for (int mt = 0; mt < 2; mt++) {
        float inv[4];
        #pragma unroll
        for (int r = 0; r < 4; r++) inv[r] = __builtin_amdgcn_rcpf(lacc[mt][r]);
        int prow = q0 + mt * 16 + quad * 4;
        #pragma unroll
        for (int dt = 0; dt < 8; dt++) {
            int d = dt * 16 + l16;
            f32x4 o = Oacc[mt][dt];
            float4 o4 = { o[0] * inv[0], o[1] * inv[1],
                          o[2] * inv[2], o[3] * inv[3] };
            *reinterpret_cast<float4*>(ob + (size_t)d * HW + prow) = o4;
        }
    }
}

// ---------------------------------------------------------------------------
extern "C" void kernel_launch(void* const* d_in, const int* in_sizes, int n_in,
                              void* d_out, int out_size, void* d_ws, size_t ws_size,
                              hipStream_t stream) {
    const float* x  = (const float*)d_in[0];
    const float* w  = (const float*)d_in[1];
    const float* ph = (const float*)d_in[2];
    const float* pw = (const float*)d_in[3];

    const size_t BHPD = (size_t)NB * NH * HW * HD;   // 8,388,608 elems
    short* Q    = (short*)d_ws;
    short* Kp   = Q + BHPD;
    short* Vt   = Kp + BHPD;
    short* xT   = Vt + BHPD;
    short* Wb   = xT + (size_t)NB * HW * CIN;
    float* outp = (float*)d_out;

    prep_xw<<<dim3(NB * 16 * 32 + 768), 256, 0, stream>>>(x, w, xT, Wb);
    qkv_proj<<<dim3(8, 12, NB), 256, 0, stream>>>(xT, Wb, ph, pw, Q, Kp, Vt);
    attn_fused<<<dim3(512), 256, 0, stream>>>(Q, Kp, Vt, outp);
}

// Round 7
// 164.654 us; speedup vs baseline: 1.0184x; 1.0184x over previous
//
#include <hip/hip_runtime.h>

#define NB 16
#define NH 4
#define HD 128
#define HW 1024
#define CIN 512

typedef short s16x8 __attribute__((ext_vector_type(8)));
typedef short s16x4 __attribute__((ext_vector_type(4)));
typedef float f32x4 __attribute__((ext_vector_type(4)));

static __device__ __forceinline__ short f2bf(float f) {
    union { float f; unsigned u; } v; v.f = f;
    unsigned r = v.u + 0x7fffu + ((v.u >> 16) & 1u);   // round-to-nearest-even
    return (short)(r >> 16);
}

// async global->LDS DMA, 16B per lane. LDS dest is wave-uniform base + lane*16
// (linear); global src is per-lane (carries the XOR swizzle).
static __device__ __forceinline__ void gload16(const short* g, short* l) {
    __builtin_amdgcn_global_load_lds(
        (const __attribute__((address_space(1))) unsigned int*)g,
        (__attribute__((address_space(3))) unsigned int*)l, 16, 0, 0);
}

// ---------------------------------------------------------------------------
// prep: x[b][c][p] fp32 -> xT[b][p][c] bf16 (32x32 LDS tile transpose)
//       W[o][c]   fp32 -> Wb bf16 (elementwise)
// ---------------------------------------------------------------------------
__global__ __launch_bounds__(256) void prep_xw(
    const float* __restrict__ x, const float* __restrict__ w,
    short* __restrict__ xT, short* __restrict__ Wb)
{
    int blk = blockIdx.x;
    if (blk < NB * 16 * 32) {                  // 8192 transpose tiles
        int b = blk >> 9, rem = blk & 511;
        int ct = rem >> 5, pt = rem & 31;      // 16 c-tiles x 32 p-tiles
        __shared__ float tile[32][33];
        int tc = threadIdx.x >> 5;             // 0..7
        int tp = threadIdx.x & 31;             // 0..31
        const float* xb = x + ((size_t)b * CIN + ct * 32) * HW + pt * 32;
        #pragma unroll
        for (int i = 0; i < 4; i++)
            tile[tc + i * 8][tp] = xb[(size_t)(tc + i * 8) * HW + tp];
        __syncthreads();
        int p = threadIdx.x >> 3, cq = threadIdx.x & 7;
        short* xo = xT + ((size_t)b * HW + pt * 32 + p) * CIN + ct * 32 + cq * 4;
        s16x4 o4 = { f2bf(tile[cq * 4 + 0][p]), f2bf(tile[cq * 4 + 1][p]),
                     f2bf(tile[cq * 4 + 2][p]), f2bf(tile[cq * 4 + 3][p]) };
        *reinterpret_cast<s16x4*>(xo) = o4;
    } else {
        int wb = blk - NB * 16 * 32;           // 0..767, 1024 elems each
        size_t base = (size_t)wb * 1024 + threadIdx.x * 4;
        const float4 v = *reinterpret_cast<const float4*>(w + base);
        s16x4 o4 = { f2bf(v.x), f2bf(v.y), f2bf(v.z), f2bf(v.w) };
        *reinterpret_cast<s16x4*>(Wb + base) = o4;
    }
}

// ---------------------------------------------------------------------------
// qkv projection GEMM, BK=64, m97 structure: global_load_lds DMA staging
// (width 16), single-buffered LDS, 2 barriers per K-step. Content keeps the
// 16B-chunk XOR swizzle (phys = c ^ (row&7)) via PRE-SWIZZLED per-lane global
// source + linear LDS dest (m173 pattern) -> frag reads & epilogues unchanged.
//   s=0: Q = val * (128^-0.5 * log2e)   [p][d]
//   s=1: K' = val + pos_h + pos_w       [p][d]
//   s=2: Vt = val                       [d][p]  -- p PERMUTED within 32-groups
//        (slot = 8*qs + 4*t + r  <-  u = 16*t + 4*qs + r), so attn's PV can
//        consume P directly from the S^T C-layout registers (no LDS trip).
// ---------------------------------------------------------------------------
__global__ __launch_bounds__(256, 3) void qkv_proj(
    const short* __restrict__ xT, const short* __restrict__ Wb,
    const float* __restrict__ pos_h, const float* __restrict__ pos_w,
    short* __restrict__ Q, short* __restrict__ Kp, short* __restrict__ Vt)
{
    __shared__ __align__(1024) char smem[34816];
    short* As = (short*)smem;               // [128][64] content-swizzled
    short* Bs = As + 128 * 64;              // [128][64] content-swizzled
    short* vb = (short*)smem;               // [128][136] reused for V epilogue

    const int pt = blockIdx.x, ot = blockIdx.y, b = blockIdx.z;
    const int tid = threadIdx.x;
    const int wave = tid >> 6, lane = tid & 63;
    const int l16 = lane & 15, quad = lane >> 4;
    const int wm = (wave & 1) * 64, wn = (wave >> 1) * 64;
    const int o0 = ot * 128, p0 = pt * 128;

    const short* xb = xT + (size_t)b * HW * CIN;

    // DMA staging geometry: wave w covers rows [w*32, w*32+32); instr j covers
    // 8 rows (1024 B). Lane: row_local = j*8 + (lane>>3), phys chunk = lane&7.
    // Source chunk = phys ^ (row&7); row&7 == lane>>3 (j*8, w*32 are 0 mod 8).
    const int r8 = lane >> 3, c8 = lane & 7;
    const int sch = c8 ^ r8;                  // pre-swizzled source chunk
    const short* wsrc = Wb + (size_t)(o0 + wave * 32 + r8) * CIN + sch * 8;
    const short* xsrc = xb + (size_t)(p0 + wave * 32 + r8) * CIN + sch * 8;
    short* adst = As + wave * 2048;           // + j*512 shorts (= j*1024 B)
    short* bdst = Bs + wave * 2048;

    f32x4 acc[4][4];
    #pragma unroll
    for (int i = 0; i < 4; i++)
        #pragma unroll
        for (int j = 0; j < 4; j++)
            acc[i][j] = f32x4{0.f, 0.f, 0.f, 0.f};

    #pragma unroll 1
    for (int kc = 0; kc < CIN; kc += 64) {
        #pragma unroll
        for (int j = 0; j < 4; j++) {
            gload16(wsrc + kc + (size_t)(j * 8) * CIN, adst + j * 512);
            gload16(xsrc + kc + (size_t)(j * 8) * CIN, bdst + j * 512);
        }
        __syncthreads();   // compiler drains vmcnt(0) before barrier
        #pragma unroll
        for (int kk = 0; kk < 2; kk++) {
            s16x8 aF[4], bF[4];
            #pragma unroll
            for (int mi = 0; mi < 4; mi++)
                aF[mi] = *(const s16x8*)(As + (wm + mi * 16 + l16) * 64
                                         + (((kk * 4 + quad) ^ (l16 & 7)) * 8));
            #pragma unroll
            for (int ni = 0; ni < 4; ni++)
                bF[ni] = *(const s16x8*)(Bs + (wn + ni * 16 + l16) * 64
                                         + (((kk * 4 + quad) ^ (l16 & 7)) * 8));
            #pragma unroll
            for (int mi = 0; mi < 4; mi++)
                #pragma unroll
                for (int ni = 0; ni < 4; ni++)
                    acc[mi][ni] = __builtin_amdgcn_mfma_f32_16x16x32_bf16(
                        aF[mi], bF[ni], acc[mi][ni], 0, 0, 0);
        }
        __syncthreads();   // all reads done before next DMA overwrites
    }

    const int s = ot >> 2, h = ot & 3;
    const size_t bh = (size_t)(b * NH + h);

    if (s == 0) {
        const float qs = 0.08838834764831845f * 1.4426950408889634f; // scale*log2e
        short* Qb = Q + bh * (size_t)(HW * HD);
        #pragma unroll
        for (int mi = 0; mi < 4; mi++) {
            int d0 = wm + mi * 16 + quad * 4;
            #pragma unroll
            for (int ni = 0; ni < 4; ni++) {
                int p = p0 + wn + ni * 16 + l16;
                f32x4 a = acc[mi][ni];
                s16x4 o4 = { f2bf(a.x * qs), f2bf(a.y * qs),
                             f2bf(a.z * qs), f2bf(a.w * qs) };
                *reinterpret_cast<s16x4*>(Qb + (size_t)p * HD + d0) = o4;
            }
        }
    } else if (s == 1) {
        short* Kb = Kp + bh * (size_t)(HW * HD);
        #pragma unroll
        for (int mi = 0; mi < 4; mi++) {
            int d0 = wm + mi * 16 + quad * 4;
            #pragma unroll
            for (int ni = 0; ni < 4; ni++) {
                int p = p0 + wn + ni * 16 + l16;
                const float4 eh = *reinterpret_cast<const float4*>(pos_h + (p >> 5) * HD + d0);
                const float4 ew = *reinterpret_cast<const float4*>(pos_w + (p & 31) * HD + d0);
                f32x4 a = acc[mi][ni];
                s16x4 o4 = { f2bf(a.x + eh.x + ew.x), f2bf(a.y + eh.y + ew.y),
                             f2bf(a.z + eh.z + ew.z), f2bf(a.w + eh.w + ew.w) };
                *reinterpret_cast<s16x4*>(Kb + (size_t)p * HD + d0) = o4;
            }
        }
    } else {
        __syncthreads();   // done with As/Bs before vb overlay
        #pragma unroll
        for (int mi = 0; mi < 4; mi++) {
            int d0 = wm + mi * 16 + quad * 4;
            #pragma unroll
            for (int ni = 0; ni < 4; ni++) {
                int p = wn + ni * 16 + l16;
                f32x4 a = acc[mi][ni];
                vb[(d0 + 0) * 136 + p] = f2bf(a.x);
                vb[(d0 + 1) * 136 + p] = f2bf(a.y);
                vb[(d0 + 2) * 136 + p] = f2bf(a.z);
                vb[(d0 + 3) * 136 + p] = f2bf(a.w);
            }
        }
        __syncthreads();
        short* Vb = Vt + bh * (size_t)(HD * HW);
        int d = tid >> 1, half = tid & 1;
        // key-permuted store: out slot group g=(half*2+(j>>2)), qs=(j&3):
        //   slots 8qs..8qs+3 (t=0) <- u = g*32 + 4qs + r
        //   slots 8qs+4..+7 (t=1) <- u = g*32 + 16 + 4qs + r
        #pragma unroll
        for (int j = 0; j < 8; j++) {
            const short* row = vb + d * 136;
            int base = (half * 2 + (j >> 2)) * 32 + (j & 3) * 4;
            s16x4 lo = *(const s16x4*)(row + base);
            s16x4 hi = *(const s16x4*)(row + base + 16);
            s16x8 v8 = { lo[0], lo[1], lo[2], lo[3],
                         hi[0], hi[1], hi[2], hi[3] };
            *reinterpret_cast<s16x8*>(Vb + (size_t)d * HW + p0 + half * 64 + j * 8) = v8;
        }
    }
}

// ---------------------------------------------------------------------------
// Fused attention: 256 threads = 4 waves x 32 Q-ROWS, kt = 64 keys x 16 iters.
// R6 (re-run; prior bench was an infra failure, no data): all 16 bV fragments
// PRELOADED into registers right after the S^T MFMA cluster (before exp2).
// bV depends only on vs (ready at iter start), so its LDS reads issue under
// the exp2 VALU phase (fills the LDS idle window) and PV's MFMAs never wait
// on LDS latency. +32 VGPR (occupancy unchanged: LDS-limited 2 blocks/CU).
// Staging via global_load_lds DMA (R5): linear LDS dest + pre-XOR'd per-lane
// global source; ONE barrier per iter (drains DMA for nxt + orders cur).
// P NEVER TOUCHES LDS (R3): V stored key-PERMUTED (see qkv_proj) so S^T's
// C-layout regs are directly PV's A-frags. Bank conflicts = 0 (verified).
// Grid 512 (bh = flat&63: XCD-affine), 2 blocks/CU (66KB LDS, grid-limited).
// ---------------------------------------------------------------------------
__global__ __launch_bounds__(256, 2) void attn_fused(
    const short* __restrict__ Q, const short* __restrict__ Kp,
    const short* __restrict__ Vt, float* __restrict__ out)
{
    __shared__ __align__(1024) short Ks[2][64 * 128];   // [buf][key][d] swz: c^(key&15)
    __shared__ __align__(1024) short Vs[2][128 * 64];   // [buf][d][slot] swz: c^(d&7)

    const int flat = blockIdx.x;
    const int qt = flat >> 6;              // 0..7
    const int bh = flat & 63;              // XCD-affine: bh%8 == blockIdx%8
    const int tid = threadIdx.x;
    const int wave = tid >> 6, lane = tid & 63;
    const int l16 = lane & 15, quad = lane >> 4;

    const short* Qb = Q + (size_t)bh * (HW * HD);
    const short* Kb = Kp + (size_t)bh * (HW * HD);
    const short* Vb = Vt + (size_t)bh * (HD * HW);

    const int q0 = qt * 128 + wave * 32;

    // Q fragments (B-operand for S^T): this wave's 32 rows, K=128 -> 2x4 frags
    s16x8 bQ[2][4];
    #pragma unroll
    for (int nt = 0; nt < 2; nt++)
        #pragma unroll
        for (int kk = 0; kk < 4; kk++)
            bQ[nt][kk] = *(const s16x8*)(Qb + (size_t)(q0 + nt * 16 + l16) * HD
                                         + kk * 32 + quad * 8);

    s16x8 ones;
    #pragma unroll
    for (int j = 0; j < 8; j++) ones[j] = (short)0x3F80;   // bf16 1.0

    f32x4 Oacc[2][8];
    #pragma unroll
    for (int mt = 0; mt < 2; mt++)
        #pragma unroll
        for (int dt = 0; dt < 8; dt++)
            Oacc[mt][dt] = f32x4{0.f, 0.f, 0.f, 0.f};
    f32x4 lacc[2] = { f32x4{0.f, 0.f, 0.f, 0.f}, f32x4{0.f, 0.f, 0.f, 0.f} };

    // DMA staging geometry (32 KB/tile = 32 instrs of 1KB; 8 per wave):
    // K instr j: keys wave*16 + j*4 .. +4. lane: key = base + (lane>>4),
    //   phys chunk = lane&15, src chunk = (lane&15) ^ (key&15),
    //   key&15 = j*4 + (lane>>4)  (wave*16 == 0 mod 16).
    // V instr j: d = wave*32 + j*8 .. +8. lane: d = base + (lane>>3),
    //   phys chunk = lane&7, src chunk = (lane&7) ^ (lane>>3)  (d&7 == lane>>3).
    const int kRow = lane >> 4;            // 0..3
    const int vRow = lane >> 3;            // 0..7
    const int vSch = (lane & 7) ^ vRow;    // V source chunk (j-independent)

    #define STAGE(buf, tile)                                                  \
        do {                                                                  \
            _Pragma("unroll")                                                 \
            for (int j = 0; j < 4; j++) {                                     \
                int kkey = wave * 16 + j * 4 + kRow;                          \
                gload16(Kb + ((size_t)((tile) * 64 + kkey)) * HD              \
                           + (((lane & 15) ^ (j * 4 + kRow)) * 8),            \
                        &Ks[buf][(wave * 16 + j * 4) * 128] + lane * 8);      \
                int vd = wave * 32 + j * 8 + vRow;                            \
                gload16(Vb + (size_t)vd * HW + (tile) * 64 + vSch * 8,        \
                        &Vs[buf][(wave * 32 + j * 8) * 64] + lane * 8);       \
            }                                                                 \
        } while (0)

    STAGE(0, 0);           // tile 0 -> buf0 (vmcnt drained by barrier below)
    __syncthreads();

    #pragma unroll 1
    for (int kt = 0; kt < 16; kt++) {
        const int cur = kt & 1, nxt = cur ^ 1;
        const short* ks = Ks[cur];
        const short* vs = Vs[cur];

        // issue DMA for tile kt+1 into nxt (overlaps this iter's compute;
        // nxt's last readers finished at iter kt-1, ordered by its barrier)
        STAGE(nxt, (kt + 1) & 15);   // wrap at end: harmless L2-hot reload

        // ---- S^T: 64 keys x 32 qrows (aK shared across both q-tiles)
        f32x4 c[4][2];
        __builtin_amdgcn_s_setprio(1);
        #pragma unroll
        for (int mtp = 0; mtp < 4; mtp++) {
            s16x8 aK[4];
            #pragma unroll
            for (int kk = 0; kk < 4; kk++)
                aK[kk] = *(const s16x8*)(ks + (mtp * 16 + l16) * 128
                                         + (((kk * 4 + quad) ^ l16) * 8));
            c[mtp][0] = f32x4{0.f, 0.f, 0.f, 0.f};
            c[mtp][1] = f32x4{0.f, 0.f, 0.f, 0.f};
            #pragma unroll
            for (int kk = 0; kk < 4; kk++) {
                c[mtp][0] = __builtin_amdgcn_mfma_f32_16x16x32_bf16(
                    aK[kk], bQ[0][kk], c[mtp][0], 0, 0, 0);
                c[mtp][1] = __builtin_amdgcn_mfma_f32_16x16x32_bf16(
                    aK[kk], bQ[1][kk], c[mtp][1], 0, 0, 0);
            }
        }
        __builtin_amdgcn_s_setprio(0);

        // ---- preload ALL V frags for this tile (no P dependence): the LDS
        //      reads issue under the exp2 phase; PV never waits on LDS.
        s16x8 bV[2][8];
        #pragma unroll
        for (int h2 = 0; h2 < 2; h2++)
            #pragma unroll
            for (int dt = 0; dt < 8; dt++)
                bV[h2][dt] = *(const s16x8*)(vs + (dt * 16 + l16) * 64
                                             + (((h2 * 4 + quad) ^ (l16 & 7)) * 8));

        // ---- P = exp2(S') packed ENTIRELY in registers (V rows permuted to
        //      match the C-layout keys each lane holds). Two 32-key halves.
        #pragma unroll
        for (int h = 0; h < 2; h++) {
            s16x8 aP[2];
            #pragma unroll
            for (int mt = 0; mt < 2; mt++) {
                f32x4 e0 = c[2 * h][mt], e1 = c[2 * h + 1][mt];
                aP[mt] = s16x8{
                    f2bf(__builtin_amdgcn_exp2f(e0[0])),
                    f2bf(__builtin_amdgcn_exp2f(e0[1])),
                    f2bf(__builtin_amdgcn_exp2f(e0[2])),
                    f2bf(__builtin_amdgcn_exp2f(e0[3])),
                    f2bf(__builtin_amdgcn_exp2f(e1[0])),
                    f2bf(__builtin_amdgcn_exp2f(e1[1])),
                    f2bf(__builtin_amdgcn_exp2f(e1[2])),
                    f2bf(__builtin_amdgcn_exp2f(e1[3])) };
            }

            __builtin_amdgcn_s_setprio(1);
            #pragma unroll
            for (int mt = 0; mt < 2; mt++)
                lacc[mt] = __builtin_amdgcn_mfma_f32_16x16x32_bf16(
                    aP[mt], ones, lacc[mt], 0, 0, 0);

            #pragma unroll
            for (int dt = 0; dt < 8; dt++) {
                #pragma unroll
                for (int mt = 0; mt < 2; mt++)
                    Oacc[mt][dt] = __builtin_amdgcn_mfma_f32_16x16x32_bf16(
                        aP[mt], bV[h][dt], Oacc[mt][dt], 0, 0, 0);
            }
            __builtin_amdgcn_s_setprio(0);
        }
        __syncthreads();   // drains DMA (nxt ready) + orders cur reads
    }
    #undef STAGE

    // epilogue: O/l, stored transposed -> out[b][h][d][p] FP32
    float* ob = out + (size_t)bh * (HD * HW);
    #pragma unroll
    for (int mt = 0; mt < 2; mt++) {
        float inv[4];
        #pragma unroll
        for (int r = 0; r < 4; r++) inv[r] = __builtin_amdgcn_rcpf(lacc[mt][r]);
        int prow = q0 + mt * 16 + quad * 4;
        #pragma unroll
        for (int dt = 0; dt < 8; dt++) {
            int d = dt * 16 + l16;
            f32x4 o = Oacc[mt][dt];
            float4 o4 = { o[0] * inv[0], o[1] * inv[1],
                          o[2] * inv[2], o[3] * inv[3] };
            *reinterpret_cast<float4*>(ob + (size_t)d * HW + prow) = o4;
        }
    }
}

// ---------------------------------------------------------------------------
extern "C" void kernel_launch(void* const* d_in, const int* in_sizes, int n_in,
                              void* d_out, int out_size, void* d_ws, size_t ws_size,
                              hipStream_t stream) {
    const float* x  = (const float*)d_in[0];
    const float* w  = (const float*)d_in[1];
    const float* ph = (const float*)d_in[2];
    const float* pw = (const float*)d_in[3];

    const size_t BHPD = (size_t)NB * NH * HW * HD;   // 8,388,608 elems
    short* Q    = (short*)d_ws;
    short* Kp   = Q + BHPD;
    short* Vt   = Kp + BHPD;
    short* xT   = Vt + BHPD;
    short* Wb   = xT + (size_t)NB * HW * CIN;
    float* outp = (float*)d_out;

    prep_xw<<<dim3(NB * 16 * 32 + 768), 256, 0, stream>>>(x, w, xT, Wb);
    qkv_proj<<<dim3(8, 12, NB), 256, 0, stream>>>(xT, Wb, ph, pw, Q, Kp, Vt);
    attn_fused<<<dim3(512), 256, 0, stream>>>(Q, Kp, Vt, outp);
}